// Round 5
// baseline (733.811 us; speedup 1.0000x reference)
//
#include <hip/hip_runtime.h>

// Masking: zero the k smallest mask_weights positions in weights.
// Exact selection on composite key (order_preserving_u32(mask) << 32) | idx,
// matching jax.lax.top_k's lower-index-first tie-breaking.
//
// Pipeline (2 launches):
//   hist1_kernel : 2048-bin histogram of mask bits (ILP x4 loads, 4 LDS replicas)
//   pass2_kernel : per-block re-derives (b1, rem1) from g_hist1, streams the
//                  masked output, collects bin-b1 candidates + 2nd-level
//                  histogram; the LAST block to finish (g_done counter) then
//                  finds b2/rem2, rank-selects the exact threshold, fixes up
//                  the candidate positions, and re-zeroes all device-global
//                  state for the next (graph-replayed) invocation.
// NOTE: no nontemporal hints — round-4 measured `nt` loads/stores collapsing
// effective BW to ~0.9 TB/s on gfx950 (pass2 78 -> 430 us). Plain cached
// accesses measured 354 us total in round 2.

#define NBINS 2048
#define CAP1 (1u << 22)   // candidate buffer (bin==b1); expected ~16K at n=32M
#define CAP2 65536u       // second-level candidates; expected ~8

__device__ unsigned int       g_hist1[NBINS];   // zero at load; re-zeroed by last block
__device__ unsigned int       g_hist2[NBINS];
__device__ unsigned int       g_count1;
__device__ unsigned int       g_count2;
__device__ unsigned int       g_done;
__device__ unsigned int       g_cand_u[CAP1];
__device__ unsigned int       g_cand_i[CAP1];
__device__ unsigned long long g_cand2[CAP2];

static __device__ __forceinline__ unsigned int xf(unsigned int b) {
  // monotonic float->uint transform (asc float order == asc unsigned order)
  return b ^ ((unsigned int)((int)b >> 31) | 0x80000000u);
}

static __device__ __forceinline__ long long compute_k(const int* mp, long long n) {
  long long m = (long long)(*mp);
  long long k = (n * (100 - m)) / 100;   // exact for mp=50; truncation matches int()
  if (k < 0) k = 0;
  if (k > n) k = n;
  return k;
}

__global__ __launch_bounds__(256) void hist1_kernel(const unsigned int* __restrict__ mb,
                                                    long long n4, long long n) {
  __shared__ unsigned int sh[4 * NBINS];  // per-wave replicas (round-2 verified config)
  const int t = threadIdx.x;
  for (int i = t; i < 4 * NBINS; i += 256) sh[i] = 0;
  __syncthreads();
  unsigned int* h = &sh[(t >> 6) * NBINS];
  const uint4* mb4 = (const uint4*)mb;
  const long long stride = (long long)gridDim.x * 1024;  // 256 threads * 4 uint4
  long long i0 = (long long)blockIdx.x * 1024 + t;
  // main loop: 4 independent loads in flight per wave (latency hiding)
  for (; i0 + 768 < n4; i0 += stride) {
    uint4 v0 = mb4[i0];
    uint4 v1 = mb4[i0 + 256];
    uint4 v2 = mb4[i0 + 512];
    uint4 v3 = mb4[i0 + 768];
    atomicAdd(&h[xf(v0.x) >> 21], 1u);
    atomicAdd(&h[xf(v0.y) >> 21], 1u);
    atomicAdd(&h[xf(v0.z) >> 21], 1u);
    atomicAdd(&h[xf(v0.w) >> 21], 1u);
    atomicAdd(&h[xf(v1.x) >> 21], 1u);
    atomicAdd(&h[xf(v1.y) >> 21], 1u);
    atomicAdd(&h[xf(v1.z) >> 21], 1u);
    atomicAdd(&h[xf(v1.w) >> 21], 1u);
    atomicAdd(&h[xf(v2.x) >> 21], 1u);
    atomicAdd(&h[xf(v2.y) >> 21], 1u);
    atomicAdd(&h[xf(v2.z) >> 21], 1u);
    atomicAdd(&h[xf(v2.w) >> 21], 1u);
    atomicAdd(&h[xf(v3.x) >> 21], 1u);
    atomicAdd(&h[xf(v3.y) >> 21], 1u);
    atomicAdd(&h[xf(v3.z) >> 21], 1u);
    atomicAdd(&h[xf(v3.w) >> 21], 1u);
  }
  // remainder groups (at most 3) for the final stripe
  for (int g = 0; g < 3; ++g) {
    long long i = i0 + (long long)g * 256;
    if (i < n4) {
      uint4 v = mb4[i];
      atomicAdd(&h[xf(v.x) >> 21], 1u);
      atomicAdd(&h[xf(v.y) >> 21], 1u);
      atomicAdd(&h[xf(v.z) >> 21], 1u);
      atomicAdd(&h[xf(v.w) >> 21], 1u);
    }
  }
  if (blockIdx.x == 0) {  // scalar tail (n % 4)
    long long rs = n4 << 2;
    if ((long long)t < n - rs) atomicAdd(&h[xf(mb[rs + t]) >> 21], 1u);
  }
  __syncthreads();
  for (int i = t; i < NBINS; i += 256) {
    unsigned int s = sh[i] + sh[i + NBINS] + sh[i + 2 * NBINS] + sh[i + 3 * NBINS];
    if (s) atomicAdd(&g_hist1[i], s);
  }
}

static __device__ __forceinline__ void cand_add(unsigned int u, unsigned int idx) {
  unsigned int s = atomicAdd(&g_count1, 1u);
  if (s < CAP1) { g_cand_u[s] = u; g_cand_i[s] = idx; }
  atomicAdd(&g_hist2[(u >> 10) & (NBINS - 1)], 1u);
}

static __device__ __forceinline__ void proc4(long long i, uint4 mv, float4 wv,
                                             float4* __restrict__ o4, long long b1) {
  unsigned int u0 = xf(mv.x), u1 = xf(mv.y), u2 = xf(mv.z), u3 = xf(mv.w);
  float4 o;
  o.x = ((long long)(u0 >> 21) < b1) ? 0.0f : wv.x;
  o.y = ((long long)(u1 >> 21) < b1) ? 0.0f : wv.y;
  o.z = ((long long)(u2 >> 21) < b1) ? 0.0f : wv.z;
  o.w = ((long long)(u3 >> 21) < b1) ? 0.0f : wv.w;
  o4[i] = o;
  long long base = i << 2;
  if ((long long)(u0 >> 21) == b1) cand_add(u0, (unsigned int)(base + 0));
  if ((long long)(u1 >> 21) == b1) cand_add(u1, (unsigned int)(base + 1));
  if ((long long)(u2 >> 21) == b1) cand_add(u2, (unsigned int)(base + 2));
  if ((long long)(u3 >> 21) == b1) cand_add(u3, (unsigned int)(base + 3));
}

__global__ __launch_bounds__(256) void pass2_kernel(const unsigned int* __restrict__ mb,
                                                    const float* __restrict__ w,
                                                    float* __restrict__ out,
                                                    const int* __restrict__ mp,
                                                    long long n4, long long n) {
  __shared__ unsigned long long tsum[256];
  __shared__ long long s_b1;
  __shared__ unsigned long long s_rem1;
  __shared__ unsigned int s_last;
  const int t = threadIdx.x;
  if (t == 0) { s_b1 = -1; s_rem1 = 0; }
  __syncthreads();
  const unsigned long long k = (unsigned long long)compute_k(mp, n);
  if (k != 0) {
    // per-block redundant select of (b1, rem1) from g_hist1
    unsigned int local[8];
    unsigned long long s = 0;
#pragma unroll
    for (int j = 0; j < 8; j++) { local[j] = g_hist1[t * 8 + j]; s += local[j]; }
    tsum[t] = s;
    __syncthreads();
    for (int off = 1; off < 256; off <<= 1) {
      unsigned long long v = (t >= off) ? tsum[t - off] : 0ull;
      __syncthreads();
      tsum[t] += v;
      __syncthreads();
    }
    unsigned long long incl = tsum[t], excl = incl - s;
    if (excl < k && k <= incl) {
      unsigned long long cum = excl;
#pragma unroll
      for (int j = 0; j < 8; j++) {
        if (cum + local[j] >= k) { s_b1 = t * 8 + j; s_rem1 = k - cum; break; }
        cum += local[j];
      }
    }
  }
  __syncthreads();
  const long long b1 = s_b1;

  const uint4*  mb4 = (const uint4*)mb;
  const float4* w4  = (const float4*)w;
  float4*       o4  = (float4*)out;
  const long long stride = (long long)gridDim.x * 512;  // 256 threads * 2 groups
  long long i0 = (long long)blockIdx.x * 512 + t;
  // 2 element-groups per iteration -> 4 loads in flight
  for (; i0 + 256 < n4; i0 += stride) {
    uint4  mv0 = mb4[i0];
    uint4  mv1 = mb4[i0 + 256];
    float4 wv0 = w4[i0];
    float4 wv1 = w4[i0 + 256];
    proc4(i0, mv0, wv0, o4, b1);
    proc4(i0 + 256, mv1, wv1, o4, b1);
  }
  if (i0 < n4) {
    uint4  mv = mb4[i0];
    float4 wv = w4[i0];
    proc4(i0, mv, wv, o4, b1);
  }
  if (blockIdx.x == 0) {  // scalar tail (n % 4)
    long long rs = n4 << 2;
    long long i = rs + t;
    if (i < n) {
      unsigned int u = xf(mb[i]);
      out[i] = ((long long)(u >> 21) < b1) ? 0.0f : w[i];
      if ((long long)(u >> 21) == b1) cand_add(u, (unsigned int)i);
    }
  }

  // ---- last-block-done: finalize + fixup + state reset (replaces 3rd launch) ----
  __threadfence();   // release: make this block's stores/atomics device-visible
  __syncthreads();
  if (t == 0) s_last = (atomicAdd(&g_done, 1u) == (unsigned int)gridDim.x - 1u) ? 1u : 0u;
  __syncthreads();
  if (!s_last) return;
  __threadfence();   // acquire: see all other blocks' candidate data

  if (k != 0) {
    __shared__ long long s_b2;
    __shared__ unsigned long long s_rem2, s_kstar;
    if (t == 0) s_kstar = 0;
    // ---- scan g_hist2 -> b2, rem2 (rank s_rem1 within second-level bins) ----
    {
      const unsigned long long k2 = s_rem1;
      unsigned int local[8];
      unsigned long long s = 0;
#pragma unroll
      for (int j = 0; j < 8; j++) { local[j] = g_hist2[t * 8 + j]; s += local[j]; }
      tsum[t] = s;
      __syncthreads();
      for (int off = 1; off < 256; off <<= 1) {
        unsigned long long v = (t >= off) ? tsum[t - off] : 0ull;
        __syncthreads();
        tsum[t] += v;
        __syncthreads();
      }
      unsigned long long incl = tsum[t], excl = incl - s;
      if (excl < k2 && k2 <= incl) {
        unsigned long long cum = excl;
#pragma unroll
        for (int j = 0; j < 8; j++) {
          if (cum + local[j] >= k2) { s_b2 = t * 8 + j; s_rem2 = k2 - cum; break; }
          cum += local[j];
        }
      }
      __syncthreads();
    }
    // ---- gather (b1,b2) candidates ----
    const unsigned int b2 = (unsigned int)s_b2;
    const unsigned int C = (g_count1 < CAP1) ? g_count1 : CAP1;
    for (unsigned int i = t; i < C; i += 256) {
      unsigned int u = g_cand_u[i];
      if (((u >> 10) & (NBINS - 1)) == b2) {
        unsigned int slot = atomicAdd(&g_count2, 1u);
        if (slot < CAP2) g_cand2[slot] = ((unsigned long long)u << 32) | (unsigned long long)g_cand_i[i];
      }
    }
    __syncthreads();
    unsigned int c2 = atomicAdd(&g_count2, 0u);
    const unsigned int C2 = (c2 < CAP2) ? c2 : CAP2;
    const unsigned long long rem2 = s_rem2;
    // rank-select the rem2-th smallest composite key (keys unique)
    for (unsigned int i = t; i < C2; i += 256) {
      unsigned long long key = g_cand2[i];
      unsigned long long cnt = 0;
      for (unsigned int j = 0; j < C2; j++) cnt += (g_cand2[j] < key) ? 1ull : 0ull;
      if (cnt + 1 == rem2) s_kstar = key + 1;  // exclusive threshold
    }
    __syncthreads();
    // ---- fixup the candidate positions ----
    const unsigned long long kstar = s_kstar;
    for (unsigned int i = t; i < C; i += 256) {
      unsigned int idx = g_cand_i[i];
      unsigned long long key = ((unsigned long long)g_cand_u[i] << 32) | (unsigned long long)idx;
      if (key < kstar) out[idx] = 0.0f;
    }
    __syncthreads();
  }
  // ---- reset device-global state for the next invocation ----
  for (int i = t; i < NBINS; i += 256) { g_hist1[i] = 0; g_hist2[i] = 0; }
  if (t == 0) { g_count1 = 0; g_count2 = 0; __threadfence(); g_done = 0; }
}

extern "C" void kernel_launch(void* const* d_in, const int* in_sizes, int n_in,
                              void* d_out, int out_size, void* d_ws, size_t ws_size,
                              hipStream_t stream) {
  const float*        w  = (const float*)d_in[0];
  const unsigned int* mb = (const unsigned int*)d_in[1];  // mask_weights bits
  const int*          mp = (const int*)d_in[2];
  float* out = (float*)d_out;
  const long long n  = (long long)in_sizes[0];
  const long long n4 = n >> 2;

  long long g1 = (n4 + 1023) / 1024;
  if (g1 < 1) g1 = 1;
  if (g1 > 1024) g1 = 1024;   // 4 blocks/CU; ILP x4 covers latency
  long long g2 = (n4 + 511) / 512;
  if (g2 < 1) g2 = 1;
  if (g2 > 2048) g2 = 2048;   // 8 blocks/CU

  hist1_kernel<<<(int)g1, 256, 0, stream>>>(mb, n4, n);
  pass2_kernel<<<(int)g2, 256, 0, stream>>>(mb, w, out, mp, n4, n);
}

// Round 6
// 355.009 us; speedup vs baseline: 2.0670x; 2.0670x over previous
//
#include <hip/hip_runtime.h>

// Masking: zero the k smallest mask_weights positions in weights.
// Exact selection on composite key (order_preserving_u32(mask) << 32) | idx,
// matching jax.lax.top_k's lower-index-first tie-breaking.
//
// Pipeline (3 launches) — round-2 verified configuration (354 us):
//   hist1_kernel : 2048-bin histogram of mask bits (ILP x4 loads)
//   pass2_kernel : per-block re-derives b1 from g_hist1, writes masked output,
//                  collects bin-b1 candidates + second-level histogram (LDS)
//   finalize     : finds b2/rem2, rank-selects exact threshold, fixes up the
//                  candidate positions, then re-zeroes all device-global
//                  state for the next invocation.
// LESSONS (measured):
//   - NO per-block device-scope __threadfence/last-block fusion: on gfx950
//     (non-coherent per-XCD L2s) a device-scope release per block forces L2
//     writebacks; fusing finalize via g_done cost pass2 78 -> 430-470 us
//     (rounds 3-5). Kernel-launch boundaries are the cheap sync here.
//   - NO __builtin_nontemporal_load/store: measured BW collapse (round 4).
// Device globals are zero-initialized at module load, and finalize restores
// that state, so no init kernel is needed.

#define NBINS 2048
#define CAP1 (1u << 22)   // candidate buffer (bin==b1)
#define CAP2 65536u       // second-level candidates

__device__ unsigned int       g_hist1[NBINS];   // zero at load; re-zeroed by finalize
__device__ unsigned int       g_hist2[NBINS];
__device__ unsigned int       g_count1;
__device__ unsigned int       g_count2;
__device__ unsigned int       g_cand_u[CAP1];
__device__ unsigned int       g_cand_i[CAP1];
__device__ unsigned long long g_cand2[CAP2];

static __device__ __forceinline__ unsigned int xf(unsigned int b) {
  // monotonic float->uint transform (asc float order == asc unsigned order)
  return b ^ ((unsigned int)((int)b >> 31) | 0x80000000u);
}

static __device__ __forceinline__ long long compute_k(const int* mp, long long n) {
  long long m = (long long)(*mp);
  long long k = (n * (100 - m)) / 100;   // exact for mp=50; truncation matches int()
  if (k < 0) k = 0;
  if (k > n) k = n;
  return k;
}

__global__ __launch_bounds__(256) void hist1_kernel(const unsigned int* __restrict__ mb,
                                                    long long n4, long long n) {
  __shared__ unsigned int sh[4 * NBINS];  // per-wave replicas
  const int t = threadIdx.x;
  for (int i = t; i < 4 * NBINS; i += 256) sh[i] = 0;
  __syncthreads();
  unsigned int* h = &sh[(t >> 6) * NBINS];
  const uint4* mb4 = (const uint4*)mb;
  const long long stride = (long long)gridDim.x * 1024;  // 256 threads * 4 uint4
  long long i0 = (long long)blockIdx.x * 1024 + t;
  // main loop: 4 independent loads in flight per wave (latency hiding)
  for (; i0 + 768 < n4; i0 += stride) {
    uint4 v0 = mb4[i0];
    uint4 v1 = mb4[i0 + 256];
    uint4 v2 = mb4[i0 + 512];
    uint4 v3 = mb4[i0 + 768];
    atomicAdd(&h[xf(v0.x) >> 21], 1u);
    atomicAdd(&h[xf(v0.y) >> 21], 1u);
    atomicAdd(&h[xf(v0.z) >> 21], 1u);
    atomicAdd(&h[xf(v0.w) >> 21], 1u);
    atomicAdd(&h[xf(v1.x) >> 21], 1u);
    atomicAdd(&h[xf(v1.y) >> 21], 1u);
    atomicAdd(&h[xf(v1.z) >> 21], 1u);
    atomicAdd(&h[xf(v1.w) >> 21], 1u);
    atomicAdd(&h[xf(v2.x) >> 21], 1u);
    atomicAdd(&h[xf(v2.y) >> 21], 1u);
    atomicAdd(&h[xf(v2.z) >> 21], 1u);
    atomicAdd(&h[xf(v2.w) >> 21], 1u);
    atomicAdd(&h[xf(v3.x) >> 21], 1u);
    atomicAdd(&h[xf(v3.y) >> 21], 1u);
    atomicAdd(&h[xf(v3.z) >> 21], 1u);
    atomicAdd(&h[xf(v3.w) >> 21], 1u);
  }
  // remainder groups (at most 3) for the final stripe
  for (int g = 0; g < 3; ++g) {
    long long i = i0 + (long long)g * 256;
    if (i < n4) {
      uint4 v = mb4[i];
      atomicAdd(&h[xf(v.x) >> 21], 1u);
      atomicAdd(&h[xf(v.y) >> 21], 1u);
      atomicAdd(&h[xf(v.z) >> 21], 1u);
      atomicAdd(&h[xf(v.w) >> 21], 1u);
    }
  }
  if (blockIdx.x == 0) {  // scalar tail (n % 4)
    long long rs = n4 << 2;
    if ((long long)t < n - rs) atomicAdd(&h[xf(mb[rs + t]) >> 21], 1u);
  }
  __syncthreads();
  for (int i = t; i < NBINS; i += 256) {
    unsigned int s = sh[i] + sh[i + NBINS] + sh[i + 2 * NBINS] + sh[i + 3 * NBINS];
    if (s) atomicAdd(&g_hist1[i], s);
  }
}

static __device__ __forceinline__ void cand_add(unsigned int u, unsigned int idx,
                                                unsigned int* __restrict__ sh2) {
  unsigned int s = atomicAdd(&g_count1, 1u);
  if (s < CAP1) { g_cand_u[s] = u; g_cand_i[s] = idx; }
  atomicAdd(&sh2[(u >> 10) & (NBINS - 1)], 1u);
}

static __device__ __forceinline__ void proc4(long long i, uint4 mv, float4 wv,
                                             float4* __restrict__ o4, long long b1,
                                             unsigned int* __restrict__ sh2) {
  unsigned int u0 = xf(mv.x), u1 = xf(mv.y), u2 = xf(mv.z), u3 = xf(mv.w);
  float4 o;
  o.x = ((long long)(u0 >> 21) < b1) ? 0.0f : wv.x;
  o.y = ((long long)(u1 >> 21) < b1) ? 0.0f : wv.y;
  o.z = ((long long)(u2 >> 21) < b1) ? 0.0f : wv.z;
  o.w = ((long long)(u3 >> 21) < b1) ? 0.0f : wv.w;
  o4[i] = o;
  long long base = i << 2;
  if ((long long)(u0 >> 21) == b1) cand_add(u0, (unsigned int)(base + 0), sh2);
  if ((long long)(u1 >> 21) == b1) cand_add(u1, (unsigned int)(base + 1), sh2);
  if ((long long)(u2 >> 21) == b1) cand_add(u2, (unsigned int)(base + 2), sh2);
  if ((long long)(u3 >> 21) == b1) cand_add(u3, (unsigned int)(base + 3), sh2);
}

__global__ __launch_bounds__(256) void pass2_kernel(const unsigned int* __restrict__ mb,
                                                    const float* __restrict__ w,
                                                    float* __restrict__ out,
                                                    const int* __restrict__ mp,
                                                    long long n4, long long n) {
  __shared__ unsigned long long tsum[256];
  __shared__ unsigned int sh2[NBINS];
  __shared__ long long s_b1;
  const int t = threadIdx.x;
  if (t == 0) s_b1 = -1;
  for (int i = t; i < NBINS; i += 256) sh2[i] = 0;
  __syncthreads();
  const unsigned long long k = (unsigned long long)compute_k(mp, n);
  if (k != 0) {
    // per-block redundant select of b1 from g_hist1 (replaces select1 kernel)
    unsigned int local[8];
    unsigned long long s = 0;
#pragma unroll
    for (int j = 0; j < 8; j++) { local[j] = g_hist1[t * 8 + j]; s += local[j]; }
    tsum[t] = s;
    __syncthreads();
    for (int off = 1; off < 256; off <<= 1) {
      unsigned long long v = (t >= off) ? tsum[t - off] : 0ull;
      __syncthreads();
      tsum[t] += v;
      __syncthreads();
    }
    unsigned long long incl = tsum[t], excl = incl - s;
    if (excl < k && k <= incl) {
      unsigned long long cum = excl;
#pragma unroll
      for (int j = 0; j < 8; j++) {
        if (cum + local[j] >= k) { s_b1 = t * 8 + j; break; }
        cum += local[j];
      }
    }
  }
  __syncthreads();
  const long long b1 = s_b1;

  const uint4*  mb4 = (const uint4*)mb;
  const float4* w4  = (const float4*)w;
  float4*       o4  = (float4*)out;
  const long long stride = (long long)gridDim.x * 512;  // 256 threads * 2 groups
  long long i0 = (long long)blockIdx.x * 512 + t;
  // 2 element-groups per iteration -> 4 loads in flight
  for (; i0 + 256 < n4; i0 += stride) {
    uint4  mv0 = mb4[i0];
    uint4  mv1 = mb4[i0 + 256];
    float4 wv0 = w4[i0];
    float4 wv1 = w4[i0 + 256];
    proc4(i0, mv0, wv0, o4, b1, sh2);
    proc4(i0 + 256, mv1, wv1, o4, b1, sh2);
  }
  if (i0 < n4) {
    uint4  mv = mb4[i0];
    float4 wv = w4[i0];
    proc4(i0, mv, wv, o4, b1, sh2);
  }
  if (blockIdx.x == 0) {  // scalar tail (n % 4)
    long long rs = n4 << 2;
    long long i = rs + t;
    if (i < n) {
      unsigned int u = xf(mb[i]);
      out[i] = ((long long)(u >> 21) < b1) ? 0.0f : w[i];
      if ((long long)(u >> 21) == b1) cand_add(u, (unsigned int)i, sh2);
    }
  }
  __syncthreads();
  for (int i = t; i < NBINS; i += 256)
    if (sh2[i]) atomicAdd(&g_hist2[i], sh2[i]);
}

__global__ __launch_bounds__(256) void finalize_kernel(const int* __restrict__ mp,
                                                       float* __restrict__ out,
                                                       long long n) {
  __shared__ unsigned long long tsum[256];
  __shared__ long long s_b2;
  __shared__ unsigned long long s_rem1, s_rem2, s_kstar;
  const int t = threadIdx.x;
  const unsigned long long k = (unsigned long long)compute_k(mp, n);
  if (k != 0) {
    if (t == 0) s_kstar = 0;
    // ---- scan g_hist1 -> rem1 (rank within bin b1) ----
    {
      unsigned int local[8];
      unsigned long long s = 0;
#pragma unroll
      for (int j = 0; j < 8; j++) { local[j] = g_hist1[t * 8 + j]; s += local[j]; }
      tsum[t] = s;
      __syncthreads();
      for (int off = 1; off < 256; off <<= 1) {
        unsigned long long v = (t >= off) ? tsum[t - off] : 0ull;
        __syncthreads();
        tsum[t] += v;
        __syncthreads();
      }
      unsigned long long incl = tsum[t], excl = incl - s;
      if (excl < k && k <= incl) {
        unsigned long long cum = excl;
#pragma unroll
        for (int j = 0; j < 8; j++) {
          if (cum + local[j] >= k) { s_rem1 = k - cum; break; }
          cum += local[j];
        }
      }
      __syncthreads();
    }
    // ---- scan g_hist2 -> b2, rem2 ----
    {
      unsigned long long k2 = s_rem1;
      __syncthreads();
      unsigned int local[8];
      unsigned long long s = 0;
#pragma unroll
      for (int j = 0; j < 8; j++) { local[j] = g_hist2[t * 8 + j]; s += local[j]; }
      tsum[t] = s;
      __syncthreads();
      for (int off = 1; off < 256; off <<= 1) {
        unsigned long long v = (t >= off) ? tsum[t - off] : 0ull;
        __syncthreads();
        tsum[t] += v;
        __syncthreads();
      }
      unsigned long long incl = tsum[t], excl = incl - s;
      if (excl < k2 && k2 <= incl) {
        unsigned long long cum = excl;
#pragma unroll
        for (int j = 0; j < 8; j++) {
          if (cum + local[j] >= k2) { s_b2 = t * 8 + j; s_rem2 = k2 - cum; break; }
          cum += local[j];
        }
      }
      __syncthreads();
    }
    // ---- gather (b1,b2) candidates ----
    const unsigned int b2 = (unsigned int)s_b2;
    const unsigned int C = (g_count1 < CAP1) ? g_count1 : CAP1;
    for (unsigned int i = t; i < C; i += 256) {
      unsigned int u = g_cand_u[i];
      if (((u >> 10) & (NBINS - 1)) == b2) {
        unsigned int slot = atomicAdd(&g_count2, 1u);
        if (slot < CAP2) g_cand2[slot] = ((unsigned long long)u << 32) | (unsigned long long)g_cand_i[i];
      }
    }
    __threadfence();
    __syncthreads();
    unsigned int c2 = atomicAdd(&g_count2, 0u);
    const unsigned int C2 = (c2 < CAP2) ? c2 : CAP2;
    const unsigned long long rem2 = s_rem2;
    // rank-select the rem2-th smallest composite key (keys unique)
    for (unsigned int i = t; i < C2; i += 256) {
      unsigned long long key = g_cand2[i];
      unsigned long long cnt = 0;
      for (unsigned int j = 0; j < C2; j++) cnt += (g_cand2[j] < key) ? 1ull : 0ull;
      if (cnt + 1 == rem2) s_kstar = key + 1;  // exclusive threshold
    }
    __syncthreads();
    // ---- fixup the candidate positions ----
    const unsigned long long kstar = s_kstar;
    for (unsigned int i = t; i < C; i += 256) {
      unsigned int idx = g_cand_i[i];
      unsigned long long key = ((unsigned long long)g_cand_u[i] << 32) | (unsigned long long)idx;
      if (key < kstar) out[idx] = 0.0f;
    }
    __syncthreads();
  }
  // ---- reset device-global state for the next invocation ----
  for (int i = t; i < NBINS; i += 256) { g_hist1[i] = 0; g_hist2[i] = 0; }
  if (t == 0) { g_count1 = 0; g_count2 = 0; }
}

extern "C" void kernel_launch(void* const* d_in, const int* in_sizes, int n_in,
                              void* d_out, int out_size, void* d_ws, size_t ws_size,
                              hipStream_t stream) {
  const float*        w  = (const float*)d_in[0];
  const unsigned int* mb = (const unsigned int*)d_in[1];  // mask_weights bits
  const int*          mp = (const int*)d_in[2];
  float* out = (float*)d_out;
  const long long n  = (long long)in_sizes[0];
  const long long n4 = n >> 2;

  long long g1 = (n4 + 1023) / 1024;
  if (g1 < 1) g1 = 1;
  if (g1 > 1024) g1 = 1024;   // 4 blocks/CU; ILP x4 covers latency
  long long g2 = (n4 + 511) / 512;
  if (g2 < 1) g2 = 1;
  if (g2 > 2048) g2 = 2048;   // 8 blocks/CU

  hist1_kernel<<<(int)g1, 256, 0, stream>>>(mb, n4, n);
  pass2_kernel<<<(int)g2, 256, 0, stream>>>(mb, w, out, mp, n4, n);
  finalize_kernel<<<1, 256, 0, stream>>>(mp, out, n);
}

// Round 10
// 353.791 us; speedup vs baseline: 2.0741x; 1.0034x over previous
//
#include <hip/hip_runtime.h>

// Masking: zero the k smallest mask_weights positions in weights.
// Exact selection on composite key (order_preserving_u32(mask) << 32) | idx,
// matching jax.lax.top_k's lower-index-first tie-breaking.
//
// CANARY ROUND: this is the round-6 verified artifact (355 us, passed twice),
// resubmitted verbatim to disambiguate 3x consecutive container failures on
// the round-7 delta (2-replica hist1 + ILP x4 pass2). If this fails too ->
// infra. If it passes -> bisect the delta.
//
// Pipeline (3 launches) — round-2 verified structure:
//   hist1_kernel : 2048-bin histogram of mask bits (ILP x4 loads)
//   pass2_kernel : per-block re-derives b1 from g_hist1, writes masked output,
//                  collects bin-b1 candidates + second-level histogram (LDS)
//   finalize     : finds b2/rem2, rank-selects exact threshold, fixes up the
//                  candidate positions, then re-zeroes all device-global
//                  state for the next invocation.
// LESSONS (measured):
//   - NO per-block device-scope __threadfence/last-block fusion: on gfx950
//     (non-coherent per-XCD L2s) a device-scope release per block forces L2
//     writebacks; fusing finalize via g_done cost pass2 78 -> 430-470 us
//     (rounds 3-5). Kernel-launch boundaries are the cheap sync here.
//   - NO __builtin_nontemporal_load/store: measured BW collapse (round 4).
//   - Mask is L3-resident in pass2 for free (round 6: pass2 FETCH = weights
//     only) — no cache hints needed.

#define NBINS 2048
#define CAP1 (1u << 22)   // candidate buffer (bin==b1)
#define CAP2 65536u       // second-level candidates

__device__ unsigned int       g_hist1[NBINS];   // zero at load; re-zeroed by finalize
__device__ unsigned int       g_hist2[NBINS];
__device__ unsigned int       g_count1;
__device__ unsigned int       g_count2;
__device__ unsigned int       g_cand_u[CAP1];
__device__ unsigned int       g_cand_i[CAP1];
__device__ unsigned long long g_cand2[CAP2];

static __device__ __forceinline__ unsigned int xf(unsigned int b) {
  // monotonic float->uint transform (asc float order == asc unsigned order)
  return b ^ ((unsigned int)((int)b >> 31) | 0x80000000u);
}

static __device__ __forceinline__ long long compute_k(const int* mp, long long n) {
  long long m = (long long)(*mp);
  long long k = (n * (100 - m)) / 100;   // exact for mp=50; truncation matches int()
  if (k < 0) k = 0;
  if (k > n) k = n;
  return k;
}

__global__ __launch_bounds__(256) void hist1_kernel(const unsigned int* __restrict__ mb,
                                                    long long n4, long long n) {
  __shared__ unsigned int sh[4 * NBINS];  // per-wave replicas
  const int t = threadIdx.x;
  for (int i = t; i < 4 * NBINS; i += 256) sh[i] = 0;
  __syncthreads();
  unsigned int* h = &sh[(t >> 6) * NBINS];
  const uint4* mb4 = (const uint4*)mb;
  const long long stride = (long long)gridDim.x * 1024;  // 256 threads * 4 uint4
  long long i0 = (long long)blockIdx.x * 1024 + t;
  // main loop: 4 independent loads in flight per wave (latency hiding)
  for (; i0 + 768 < n4; i0 += stride) {
    uint4 v0 = mb4[i0];
    uint4 v1 = mb4[i0 + 256];
    uint4 v2 = mb4[i0 + 512];
    uint4 v3 = mb4[i0 + 768];
    atomicAdd(&h[xf(v0.x) >> 21], 1u);
    atomicAdd(&h[xf(v0.y) >> 21], 1u);
    atomicAdd(&h[xf(v0.z) >> 21], 1u);
    atomicAdd(&h[xf(v0.w) >> 21], 1u);
    atomicAdd(&h[xf(v1.x) >> 21], 1u);
    atomicAdd(&h[xf(v1.y) >> 21], 1u);
    atomicAdd(&h[xf(v1.z) >> 21], 1u);
    atomicAdd(&h[xf(v1.w) >> 21], 1u);
    atomicAdd(&h[xf(v2.x) >> 21], 1u);
    atomicAdd(&h[xf(v2.y) >> 21], 1u);
    atomicAdd(&h[xf(v2.z) >> 21], 1u);
    atomicAdd(&h[xf(v2.w) >> 21], 1u);
    atomicAdd(&h[xf(v3.x) >> 21], 1u);
    atomicAdd(&h[xf(v3.y) >> 21], 1u);
    atomicAdd(&h[xf(v3.z) >> 21], 1u);
    atomicAdd(&h[xf(v3.w) >> 21], 1u);
  }
  // remainder groups (at most 3) for the final stripe
  for (int g = 0; g < 3; ++g) {
    long long i = i0 + (long long)g * 256;
    if (i < n4) {
      uint4 v = mb4[i];
      atomicAdd(&h[xf(v.x) >> 21], 1u);
      atomicAdd(&h[xf(v.y) >> 21], 1u);
      atomicAdd(&h[xf(v.z) >> 21], 1u);
      atomicAdd(&h[xf(v.w) >> 21], 1u);
    }
  }
  if (blockIdx.x == 0) {  // scalar tail (n % 4)
    long long rs = n4 << 2;
    if ((long long)t < n - rs) atomicAdd(&h[xf(mb[rs + t]) >> 21], 1u);
  }
  __syncthreads();
  for (int i = t; i < NBINS; i += 256) {
    unsigned int s = sh[i] + sh[i + NBINS] + sh[i + 2 * NBINS] + sh[i + 3 * NBINS];
    if (s) atomicAdd(&g_hist1[i], s);
  }
}

static __device__ __forceinline__ void cand_add(unsigned int u, unsigned int idx,
                                                unsigned int* __restrict__ sh2) {
  unsigned int s = atomicAdd(&g_count1, 1u);
  if (s < CAP1) { g_cand_u[s] = u; g_cand_i[s] = idx; }
  atomicAdd(&sh2[(u >> 10) & (NBINS - 1)], 1u);
}

static __device__ __forceinline__ void proc4(long long i, uint4 mv, float4 wv,
                                             float4* __restrict__ o4, long long b1,
                                             unsigned int* __restrict__ sh2) {
  unsigned int u0 = xf(mv.x), u1 = xf(mv.y), u2 = xf(mv.z), u3 = xf(mv.w);
  float4 o;
  o.x = ((long long)(u0 >> 21) < b1) ? 0.0f : wv.x;
  o.y = ((long long)(u1 >> 21) < b1) ? 0.0f : wv.y;
  o.z = ((long long)(u2 >> 21) < b1) ? 0.0f : wv.z;
  o.w = ((long long)(u3 >> 21) < b1) ? 0.0f : wv.w;
  o4[i] = o;
  long long base = i << 2;
  if ((long long)(u0 >> 21) == b1) cand_add(u0, (unsigned int)(base + 0), sh2);
  if ((long long)(u1 >> 21) == b1) cand_add(u1, (unsigned int)(base + 1), sh2);
  if ((long long)(u2 >> 21) == b1) cand_add(u2, (unsigned int)(base + 2), sh2);
  if ((long long)(u3 >> 21) == b1) cand_add(u3, (unsigned int)(base + 3), sh2);
}

__global__ __launch_bounds__(256) void pass2_kernel(const unsigned int* __restrict__ mb,
                                                    const float* __restrict__ w,
                                                    float* __restrict__ out,
                                                    const int* __restrict__ mp,
                                                    long long n4, long long n) {
  __shared__ unsigned long long tsum[256];
  __shared__ unsigned int sh2[NBINS];
  __shared__ long long s_b1;
  const int t = threadIdx.x;
  if (t == 0) s_b1 = -1;
  for (int i = t; i < NBINS; i += 256) sh2[i] = 0;
  __syncthreads();
  const unsigned long long k = (unsigned long long)compute_k(mp, n);
  if (k != 0) {
    // per-block redundant select of b1 from g_hist1 (replaces select1 kernel)
    unsigned int local[8];
    unsigned long long s = 0;
#pragma unroll
    for (int j = 0; j < 8; j++) { local[j] = g_hist1[t * 8 + j]; s += local[j]; }
    tsum[t] = s;
    __syncthreads();
    for (int off = 1; off < 256; off <<= 1) {
      unsigned long long v = (t >= off) ? tsum[t - off] : 0ull;
      __syncthreads();
      tsum[t] += v;
      __syncthreads();
    }
    unsigned long long incl = tsum[t], excl = incl - s;
    if (excl < k && k <= incl) {
      unsigned long long cum = excl;
#pragma unroll
      for (int j = 0; j < 8; j++) {
        if (cum + local[j] >= k) { s_b1 = t * 8 + j; break; }
        cum += local[j];
      }
    }
  }
  __syncthreads();
  const long long b1 = s_b1;

  const uint4*  mb4 = (const uint4*)mb;
  const float4* w4  = (const float4*)w;
  float4*       o4  = (float4*)out;
  const long long stride = (long long)gridDim.x * 512;  // 256 threads * 2 groups
  long long i0 = (long long)blockIdx.x * 512 + t;
  // 2 element-groups per iteration -> 4 loads in flight
  for (; i0 + 256 < n4; i0 += stride) {
    uint4  mv0 = mb4[i0];
    uint4  mv1 = mb4[i0 + 256];
    float4 wv0 = w4[i0];
    float4 wv1 = w4[i0 + 256];
    proc4(i0, mv0, wv0, o4, b1, sh2);
    proc4(i0 + 256, mv1, wv1, o4, b1, sh2);
  }
  if (i0 < n4) {
    uint4  mv = mb4[i0];
    float4 wv = w4[i0];
    proc4(i0, mv, wv, o4, b1, sh2);
  }
  if (blockIdx.x == 0) {  // scalar tail (n % 4)
    long long rs = n4 << 2;
    long long i = rs + t;
    if (i < n) {
      unsigned int u = xf(mb[i]);
      out[i] = ((long long)(u >> 21) < b1) ? 0.0f : w[i];
      if ((long long)(u >> 21) == b1) cand_add(u, (unsigned int)i, sh2);
    }
  }
  __syncthreads();
  for (int i = t; i < NBINS; i += 256)
    if (sh2[i]) atomicAdd(&g_hist2[i], sh2[i]);
}

__global__ __launch_bounds__(256) void finalize_kernel(const int* __restrict__ mp,
                                                       float* __restrict__ out,
                                                       long long n) {
  __shared__ unsigned long long tsum[256];
  __shared__ long long s_b2;
  __shared__ unsigned long long s_rem1, s_rem2, s_kstar;
  const int t = threadIdx.x;
  const unsigned long long k = (unsigned long long)compute_k(mp, n);
  if (k != 0) {
    if (t == 0) s_kstar = 0;
    // ---- scan g_hist1 -> rem1 (rank within bin b1) ----
    {
      unsigned int local[8];
      unsigned long long s = 0;
#pragma unroll
      for (int j = 0; j < 8; j++) { local[j] = g_hist1[t * 8 + j]; s += local[j]; }
      tsum[t] = s;
      __syncthreads();
      for (int off = 1; off < 256; off <<= 1) {
        unsigned long long v = (t >= off) ? tsum[t - off] : 0ull;
        __syncthreads();
        tsum[t] += v;
        __syncthreads();
      }
      unsigned long long incl = tsum[t], excl = incl - s;
      if (excl < k && k <= incl) {
        unsigned long long cum = excl;
#pragma unroll
        for (int j = 0; j < 8; j++) {
          if (cum + local[j] >= k) { s_rem1 = k - cum; break; }
          cum += local[j];
        }
      }
      __syncthreads();
    }
    // ---- scan g_hist2 -> b2, rem2 ----
    {
      unsigned long long k2 = s_rem1;
      __syncthreads();
      unsigned int local[8];
      unsigned long long s = 0;
#pragma unroll
      for (int j = 0; j < 8; j++) { local[j] = g_hist2[t * 8 + j]; s += local[j]; }
      tsum[t] = s;
      __syncthreads();
      for (int off = 1; off < 256; off <<= 1) {
        unsigned long long v = (t >= off) ? tsum[t - off] : 0ull;
        __syncthreads();
        tsum[t] += v;
        __syncthreads();
      }
      unsigned long long incl = tsum[t], excl = incl - s;
      if (excl < k2 && k2 <= incl) {
        unsigned long long cum = excl;
#pragma unroll
        for (int j = 0; j < 8; j++) {
          if (cum + local[j] >= k2) { s_b2 = t * 8 + j; s_rem2 = k2 - cum; break; }
          cum += local[j];
        }
      }
      __syncthreads();
    }
    // ---- gather (b1,b2) candidates ----
    const unsigned int b2 = (unsigned int)s_b2;
    const unsigned int C = (g_count1 < CAP1) ? g_count1 : CAP1;
    for (unsigned int i = t; i < C; i += 256) {
      unsigned int u = g_cand_u[i];
      if (((u >> 10) & (NBINS - 1)) == b2) {
        unsigned int slot = atomicAdd(&g_count2, 1u);
        if (slot < CAP2) g_cand2[slot] = ((unsigned long long)u << 32) | (unsigned long long)g_cand_i[i];
      }
    }
    __threadfence();
    __syncthreads();
    unsigned int c2 = atomicAdd(&g_count2, 0u);
    const unsigned int C2 = (c2 < CAP2) ? c2 : CAP2;
    const unsigned long long rem2 = s_rem2;
    // rank-select the rem2-th smallest composite key (keys unique)
    for (unsigned int i = t; i < C2; i += 256) {
      unsigned long long key = g_cand2[i];
      unsigned long long cnt = 0;
      for (unsigned int j = 0; j < C2; j++) cnt += (g_cand2[j] < key) ? 1ull : 0ull;
      if (cnt + 1 == rem2) s_kstar = key + 1;  // exclusive threshold
    }
    __syncthreads();
    // ---- fixup the candidate positions ----
    const unsigned long long kstar = s_kstar;
    for (unsigned int i = t; i < C; i += 256) {
      unsigned int idx = g_cand_i[i];
      unsigned long long key = ((unsigned long long)g_cand_u[i] << 32) | (unsigned long long)idx;
      if (key < kstar) out[idx] = 0.0f;
    }
    __syncthreads();
  }
  // ---- reset device-global state for the next invocation ----
  for (int i = t; i < NBINS; i += 256) { g_hist1[i] = 0; g_hist2[i] = 0; }
  if (t == 0) { g_count1 = 0; g_count2 = 0; }
}

extern "C" void kernel_launch(void* const* d_in, const int* in_sizes, int n_in,
                              void* d_out, int out_size, void* d_ws, size_t ws_size,
                              hipStream_t stream) {
  const float*        w  = (const float*)d_in[0];
  const unsigned int* mb = (const unsigned int*)d_in[1];  // mask_weights bits
  const int*          mp = (const int*)d_in[2];
  float* out = (float*)d_out;
  const long long n  = (long long)in_sizes[0];
  const long long n4 = n >> 2;

  long long g1 = (n4 + 1023) / 1024;
  if (g1 < 1) g1 = 1;
  if (g1 > 1024) g1 = 1024;   // 4 blocks/CU; ILP x4 covers latency
  long long g2 = (n4 + 511) / 512;
  if (g2 < 1) g2 = 1;
  if (g2 > 2048) g2 = 2048;   // 8 blocks/CU

  hist1_kernel<<<(int)g1, 256, 0, stream>>>(mb, n4, n);
  pass2_kernel<<<(int)g2, 256, 0, stream>>>(mb, w, out, mp, n4, n);
  finalize_kernel<<<1, 256, 0, stream>>>(mp, out, n);
}